// Round 2
// baseline (610.599 us; speedup 1.0000x reference)
//
#include <hip/hip_runtime.h>
#include <hip/hip_bf16.h>
#include <cstdint>

typedef unsigned short u16;
typedef unsigned int   u32;
typedef __bf16 bf16x8 __attribute__((ext_vector_type(8)));
typedef float  f32x4  __attribute__((ext_vector_type(4)));

#define S_    512
#define D_    128
#define H_    128
#define NPOS_ (S_ * S_)      // 262144 rows
#define LN_EPS 1e-5f

// ---------- small helpers ----------
// fast RNE float->bf16 (bit trick, ~4 VALU vs ~6-8 for library cvt)
__device__ __forceinline__ u16 f2bf(float f) {
  u32 u = __float_as_uint(f);
  u += 0x7fff + ((u >> 16) & 1);
  return (u16)(u >> 16);
}
__device__ __forceinline__ u32 f2bf2(float lo, float hi) {
  u32 a = __float_as_uint(lo); a += 0x7fff + ((a >> 16) & 1);
  u32 b = __float_as_uint(hi); b += 0x7fff + ((b >> 16) & 1);
  return (a >> 16) | (b & 0xffff0000u);
}
__device__ __forceinline__ float bflo(u32 p) { return __uint_as_float(p << 16); }
__device__ __forceinline__ float bfhi(u32 p) { return __uint_as_float(p & 0xffff0000u); }
__device__ __forceinline__ float bf2f(u16 v) { return __uint_as_float((u32)v << 16); }
// fast sigmoid: v_mul+v_exp+v_add+v_rcp (no IEEE divide sequence)
__device__ __forceinline__ float sigmoidf_(float x) {
  return __builtin_amdgcn_rcpf(1.f + __expf(-x));
}

__device__ __forceinline__ void gld16(const void* g, void* l) {
  __builtin_amdgcn_global_load_lds(
      (const __attribute__((address_space(1))) void*)g,
      (__attribute__((address_space(3))) void*)l, 16, 0, 0);
}

// XOR-swizzled global->LDS stage: LDS chunk (row,colL) holds global chunk
// (row, colL ^ (row & (CPR-1))).  Kills the 16-way bank conflict of 128B-row
// tiles (quad lanes 0-15 all hitting banks 0-3) down to 2-way (free, m136).
template <int CPR, int TOTAL, int THREADS>
__device__ __forceinline__ void stage_sw(const char* gbase, int ld_bytes, char* lds, int tid) {
#pragma unroll
  for (int c = tid; c < TOTAL; c += THREADS) {
    int row  = c / CPR;
    int colL = c & (CPR - 1);
    int colG = colL ^ (row & (CPR - 1));
    gld16(gbase + (size_t)row * ld_bytes + (size_t)colG * 16, lds + (size_t)c * 16);
  }
}
// matching fragment reads (ko is a multiple of 8 -> 16B chunk aligned)
__device__ __forceinline__ bf16x8 frag8(const u16* lds, int row, int ko) {   // 8 chunks/row (128B)
  int chunk = (ko >> 3) ^ (row & 7);
  return *(const bf16x8*)&lds[row * 64 + (chunk << 3)];
}
__device__ __forceinline__ bf16x8 frag16(const u16* lds, int row, int ko) {  // 16 chunks/row (256B)
  int chunk = (ko >> 3) ^ (row & 15);
  return *(const bf16x8*)&lds[row * 128 + (chunk << 3)];
}

// ---------- kernel 0: cast weights to bf16 ----------
// wb layout: [0]=Wl [1]=Wlg [2]=Wr [3]=Wrg [4]=Wog [5]=Wout, each 128x128 row-major (K-contig)
__global__ __launch_bounds__(256) void k_prep(
    const float* __restrict__ wl, const float* __restrict__ wlg,
    const float* __restrict__ wr, const float* __restrict__ wrg,
    const float* __restrict__ wog, const float* __restrict__ wout,
    u16* __restrict__ wb) {
  int i = blockIdx.x * 256 + threadIdx.x;   // < 6*16384 exactly
  int m = i >> 14, o = i & 16383;
  const float* src = (m == 0) ? wl : (m == 1) ? wlg : (m == 2) ? wr
                   : (m == 3) ? wrg : (m == 4) ? wog : wout;
  wb[i] = f2bf(src[o]);
}

// ---------- kernel 1: layernorm(x) -> xn bf16 [r][d] ----------
__global__ __launch_bounds__(256) void k_ln(
    const float* __restrict__ x, const float* __restrict__ ng,
    const float* __restrict__ nb, u32* __restrict__ xn) {
  const int l  = threadIdx.x & 63;
  const int wid = (blockIdx.x * 256 + threadIdx.x) >> 6;
  const int nw  = (gridDim.x * 256) >> 6;
  const float2 gg = ((const float2*)ng)[l];
  const float2 bb = ((const float2*)nb)[l];
  for (int row = wid; row < NPOS_; row += nw) {
    float2 v = ((const float2*)(x + (size_t)row * D_))[l];
    float s = v.x + v.y;
    float q = v.x * v.x + v.y * v.y;
#pragma unroll
    for (int off = 32; off >= 1; off >>= 1) {
      s += __shfl_xor(s, off);
      q += __shfl_xor(q, off);
    }
    float mu  = s * (1.f / 128.f);
    float var = q * (1.f / 128.f) - mu * mu;
    float rs  = rsqrtf(var + LN_EPS);
    float a = (v.x - mu) * rs * gg.x + bb.x;
    float b = (v.y - mu) * rs * gg.y + bb.y;
    xn[(size_t)row * 64 + l] = f2bf2(a, b);
  }
}

// ---------- kernel 2a: value+gate projections, wave-specialized ----------
// 512 threads: waves 0-3 compute C_v[h][r] = W_v . xn^T, waves 4-7 C_g = W_g . xn^T.
// Gate waves push sigmoid(C_g) through LDS (identical fragment coords lane-for-lane),
// value waves combine  v * mask * sig  and store channel-major.
// g = blockIdx.y: 0 -> (Wl,Wlg)->left_t, 1 -> (Wr,Wrg)->right_t
__global__ __launch_bounds__(512, 4) void k_proj_pair(
    const u16* __restrict__ xn, const float* __restrict__ mask,
    const u16* __restrict__ wb, u16* __restrict__ left_t,
    u16* __restrict__ right_t) {
  __shared__ u16 Bs[128 * 64];       // xn tile (k-half)
  __shared__ u16 As[2 * 128 * 64];   // [role][h][k-half]; reused as sigmoid exchange
  const int g   = blockIdx.y;
  const int r0  = blockIdx.x * 128;
  const int tid = threadIdx.x;
  const int w = tid >> 6, l = tid & 63;
  const int role = w >> 2, sub = w & 3;        // role 0=value, 1=gate
  const int wr = sub >> 1, wc = sub & 1;
  const u16* Wv = wb + (size_t)(2 * g) * (H_ * D_);
  const u16* Wg = Wv + H_ * D_;
  const u16* Amine = As + role * (128 * 64);

  const f32x4 vz = {0.f, 0.f, 0.f, 0.f};
  f32x4 acc[4][4];
#pragma unroll
  for (int i = 0; i < 4; ++i)
#pragma unroll
    for (int j = 0; j < 4; ++j) acc[i][j] = vz;

#pragma unroll
  for (int kt = 0; kt < 2; ++kt) {
    stage_sw<8, 1024, 512>((const char*)xn + ((size_t)r0 * D_ + kt * 64) * 2, D_ * 2, (char*)Bs, tid);
    stage_sw<8, 1024, 512>((const char*)Wv + (size_t)(kt * 64) * 2, D_ * 2, (char*)As, tid);
    stage_sw<8, 1024, 512>((const char*)Wg + (size_t)(kt * 64) * 2, D_ * 2, (char*)(As + 128 * 64), tid);
    __syncthreads();
#pragma unroll
    for (int kk = 0; kk < 2; ++kk) {
      const int ko = kk * 32 + (l >> 4) * 8;
      bf16x8 bfr[4];
#pragma unroll
      for (int ni = 0; ni < 4; ++ni)
        bfr[ni] = frag8(Bs, wc * 64 + ni * 16 + (l & 15), ko);
#pragma unroll
      for (int mi = 0; mi < 4; ++mi) {
        bf16x8 a = frag8(Amine, wr * 64 + mi * 16 + (l & 15), ko);
#pragma unroll
        for (int ni = 0; ni < 4; ++ni)
          acc[mi][ni] = __builtin_amdgcn_mfma_f32_16x16x32_bf16(a, bfr[ni], acc[mi][ni], 0, 0, 0);
      }
    }
    __syncthreads();
  }

  const int quad = l >> 4, lc = l & 15;
  u16* G = As;  // 4 subs * 64 idx * 64 lanes * bf16 = 32 KB, conflict-free rows
  if (role == 1) {
#pragma unroll
    for (int mi = 0; mi < 4; ++mi)
#pragma unroll
      for (int ni = 0; ni < 4; ++ni)
#pragma unroll
        for (int reg = 0; reg < 4; ++reg) {
          int idx = (mi * 4 + ni) * 4 + reg;
          G[(sub * 64 + idx) * 64 + l] = f2bf(sigmoidf_(acc[mi][ni][reg]));
        }
  }
  __syncthreads();
  if (role == 0) {
    u16* dst = (g == 0) ? left_t : right_t;
    float mk[4];
#pragma unroll
    for (int ni = 0; ni < 4; ++ni) mk[ni] = mask[r0 + wc * 64 + ni * 16 + lc];
#pragma unroll
    for (int mi = 0; mi < 4; ++mi)
#pragma unroll
      for (int ni = 0; ni < 4; ++ni)
#pragma unroll
        for (int reg = 0; reg < 4; ++reg) {
          int idx = (mi * 4 + ni) * 4 + reg;
          float sg = bf2f(G[(sub * 64 + idx) * 64 + l]);
          int r = r0 + wc * 64 + ni * 16 + lc;
          int hrow = wr * 64 + mi * 16 + quad * 4 + reg;
          dst[(size_t)hrow * NPOS_ + r] = f2bf(acc[mi][ni][reg] * mk[ni] * sg);
        }
  }
}

// ---------- kernel 2b: out-gate projection: sigmoid(xn @ Wog^T) -> gate_t ----------
__global__ __launch_bounds__(256, 4) void k_proj_gate(
    const u16* __restrict__ xn, const u16* __restrict__ wb,
    u16* __restrict__ gate_t) {
  __shared__ u16 Bs[128 * 64];
  __shared__ u16 As0[128 * 64];
  const int r0  = blockIdx.x * 128;
  const int tid = threadIdx.x;
  const int w = tid >> 6, l = tid & 63;
  const int wr = w >> 1, wc = w & 1;
  const u16* W0 = wb + (size_t)4 * (H_ * D_);

  const f32x4 vz = {0.f, 0.f, 0.f, 0.f};
  f32x4 acc[4][4];
#pragma unroll
  for (int i = 0; i < 4; ++i)
#pragma unroll
    for (int j = 0; j < 4; ++j) acc[i][j] = vz;

#pragma unroll
  for (int kt = 0; kt < 2; ++kt) {
    stage_sw<8, 1024, 256>((const char*)xn + ((size_t)r0 * D_ + kt * 64) * 2, D_ * 2, (char*)Bs, tid);
    stage_sw<8, 1024, 256>((const char*)W0 + (size_t)(kt * 64) * 2, D_ * 2, (char*)As0, tid);
    __syncthreads();
#pragma unroll
    for (int kk = 0; kk < 2; ++kk) {
      const int ko = kk * 32 + (l >> 4) * 8;
      bf16x8 bfr[4];
#pragma unroll
      for (int ni = 0; ni < 4; ++ni)
        bfr[ni] = frag8(Bs, wc * 64 + ni * 16 + (l & 15), ko);
#pragma unroll
      for (int mi = 0; mi < 4; ++mi) {
        bf16x8 a = frag8(As0, wr * 64 + mi * 16 + (l & 15), ko);
#pragma unroll
        for (int ni = 0; ni < 4; ++ni)
          acc[mi][ni] = __builtin_amdgcn_mfma_f32_16x16x32_bf16(a, bfr[ni], acc[mi][ni], 0, 0, 0);
      }
    }
    __syncthreads();
  }

  const int quad = l >> 4, lc = l & 15;
#pragma unroll
  for (int ni = 0; ni < 4; ++ni) {
    const int r = r0 + wc * 64 + ni * 16 + lc;
#pragma unroll
    for (int mi = 0; mi < 4; ++mi)
#pragma unroll
      for (int reg = 0; reg < 4; ++reg) {
        const int hrow = wr * 64 + mi * 16 + quad * 4 + reg;
        gate_t[(size_t)hrow * NPOS_ + r] = f2bf(sigmoidf_(acc[mi][ni][reg]));
      }
  }
}

// ---------- kernel 3: per-channel einsum GEMM ----------
// out_t[d][i*512+j] = sum_k left_t[d][i*512+k] * right_t[d][j*512+k]
__global__ __launch_bounds__(256, 4) void k_einsum(
    const u16* __restrict__ left_t, const u16* __restrict__ right_t,
    u16* __restrict__ out_t) {
  const int d = blockIdx.x;         // channel; x-fastest => XCD = d%8 locality
  const int t = blockIdx.y;         // 0..15 -> 4x4 (i,j) tiles
  const int i0 = (t >> 2) * 128, j0 = (t & 3) * 128;
  __shared__ u16 As[128 * 64], Bs[128 * 64];
  const u16* L = left_t + (size_t)d * NPOS_;
  const u16* R = right_t + (size_t)d * NPOS_;
  const int tid = threadIdx.x;
  const int w = tid >> 6, l = tid & 63;
  const int wr = w >> 1, wc = w & 1;

  const f32x4 vz = {0.f, 0.f, 0.f, 0.f};
  f32x4 acc[4][4];
#pragma unroll
  for (int i = 0; i < 4; ++i)
#pragma unroll
    for (int j = 0; j < 4; ++j) acc[i][j] = vz;

  for (int kt = 0; kt < 8; ++kt) {
    stage_sw<8, 1024, 256>((const char*)L + ((size_t)i0 * S_ + kt * 64) * 2, S_ * 2, (char*)As, tid);
    stage_sw<8, 1024, 256>((const char*)R + ((size_t)j0 * S_ + kt * 64) * 2, S_ * 2, (char*)Bs, tid);
    __syncthreads();
#pragma unroll
    for (int kk = 0; kk < 2; ++kk) {
      const int ko = kk * 32 + (l >> 4) * 8;
      bf16x8 a[4], b[4];
#pragma unroll
      for (int mi = 0; mi < 4; ++mi)
        a[mi] = frag8(As, wr * 64 + mi * 16 + (l & 15), ko);
#pragma unroll
      for (int ni = 0; ni < 4; ++ni)
        b[ni] = frag8(Bs, wc * 64 + ni * 16 + (l & 15), ko);
#pragma unroll
      for (int mi = 0; mi < 4; ++mi)
#pragma unroll
        for (int ni = 0; ni < 4; ++ni)
          acc[mi][ni] = __builtin_amdgcn_mfma_f32_16x16x32_bf16(a[mi], b[ni], acc[mi][ni], 0, 0, 0);
    }
    __syncthreads();
  }

  const int quad = l >> 4, lc = l & 15;
  u16* O = out_t + (size_t)d * NPOS_;
#pragma unroll
  for (int mi = 0; mi < 4; ++mi)
#pragma unroll
    for (int ni = 0; ni < 4; ++ni) {
      const int col = j0 + wc * 64 + ni * 16 + lc;
#pragma unroll
      for (int reg = 0; reg < 4; ++reg) {
        const int row = i0 + wr * 64 + mi * 16 + quad * 4 + reg;
        O[(size_t)row * S_ + col] = f2bf(acc[mi][ni][reg]);
      }
    }
}

// ---------- kernel 4: out-LN over H, gate, @Wout^T ----------
__global__ __launch_bounds__(256, 2) void k_final(
    const u16* __restrict__ out_t, const u16* __restrict__ gate_t,
    const float* __restrict__ og, const float* __restrict__ ob,
    const u16* __restrict__ wout_b, float* __restrict__ out) {
  __shared__ u16 A_lds[128 * 136];   // [position j][h], padded stride (272B = 17*16, b128-aligned)
  __shared__ u16 Wlds[128 * 128];    // Wout [dout][h], XOR-swizzled chunks
  __shared__ float psum[4][128], pq[4][128];
  __shared__ float mu_s[128], rs_s[128];
  const int tid = threadIdx.x, w = tid >> 6, l = tid & 63;
  const int r0 = blockIdx.x * 128;

  stage_sw<16, 2048, 256>((const char*)wout_b, 256, (char*)Wlds, tid);

  // pass 1: stats over channels, lane owns positions 2l, 2l+1
  float s0 = 0.f, s1 = 0.f, q0 = 0.f, q1 = 0.f;
  for (int it = 0; it < 32; ++it) {
    int d = it * 4 + w;
    u32 p = *(const u32*)&out_t[(size_t)d * NPOS_ + r0 + 2 * l];
    float f0 = bflo(p), f1 = bfhi(p);
    s0 += f0; s1 += f1; q0 += f0 * f0; q1 += f1 * f1;
  }
  psum[w][2 * l] = s0; psum[w][2 * l + 1] = s1;
  pq[w][2 * l] = q0;   pq[w][2 * l + 1] = q1;
  __syncthreads();
  if (tid < 128) {
    float s = psum[0][tid] + psum[1][tid] + psum[2][tid] + psum[3][tid];
    float q = pq[0][tid] + pq[1][tid] + pq[2][tid] + pq[3][tid];
    float mu  = s * (1.f / 128.f);
    float var = q * (1.f / 128.f) - mu * mu;
    mu_s[tid] = mu;
    rs_s[tid] = rsqrtf(var + LN_EPS);
  }
  __syncthreads();

  // pass 2 (L2-hot reload): normalize*gate -> bf16 A tile [j][h]
  for (int it = 0; it < 32; ++it) {
    int d = it * 4 + w;
    u32 p  = *(const u32*)&out_t[(size_t)d * NPOS_ + r0 + 2 * l];
    u32 gp = *(const u32*)&gate_t[(size_t)d * NPOS_ + r0 + 2 * l];
    float gd = og[d], bd = ob[d];
    float f0 = bflo(p), f1 = bfhi(p);
    float g0 = bflo(gp), g1 = bfhi(gp);
    int ja = 2 * l, jb = 2 * l + 1;
    A_lds[(size_t)ja * 136 + d] = f2bf(((f0 - mu_s[ja]) * rs_s[ja] * gd + bd) * g0);
    A_lds[(size_t)jb * 136 + d] = f2bf(((f1 - mu_s[jb]) * rs_s[jb] * gd + bd) * g1);
  }
  __syncthreads();

  // GEMM: out[r0+j][dout] = sum_h A[j][h] * Wout[dout][h]
  const int wr = w >> 1, wc = w & 1;
  const f32x4 vz = {0.f, 0.f, 0.f, 0.f};
  f32x4 acc[4][4];
#pragma unroll
  for (int i = 0; i < 4; ++i)
#pragma unroll
    for (int j = 0; j < 4; ++j) acc[i][j] = vz;
#pragma unroll
  for (int kk = 0; kk < 4; ++kk) {
    const int ko = kk * 32 + (l >> 4) * 8;
    bf16x8 a[4], b[4];
#pragma unroll
    for (int mi = 0; mi < 4; ++mi)
      a[mi] = *(const bf16x8*)&A_lds[(wr * 64 + mi * 16 + (l & 15)) * 136 + ko];
#pragma unroll
    for (int ni = 0; ni < 4; ++ni)
      b[ni] = frag16(Wlds, wc * 64 + ni * 16 + (l & 15), ko);
#pragma unroll
    for (int mi = 0; mi < 4; ++mi)
#pragma unroll
      for (int ni = 0; ni < 4; ++ni)
        acc[mi][ni] = __builtin_amdgcn_mfma_f32_16x16x32_bf16(a[mi], b[ni], acc[mi][ni], 0, 0, 0);
  }
  const int quad = l >> 4, lc = l & 15;
#pragma unroll
  for (int mi = 0; mi < 4; ++mi)
#pragma unroll
    for (int ni = 0; ni < 4; ++ni) {
      const int dout = wc * 64 + ni * 16 + lc;
#pragma unroll
      for (int reg = 0; reg < 4; ++reg) {
        const int row = r0 + wr * 64 + mi * 16 + quad * 4 + reg;
        out[(size_t)row * D_ + dout] = acc[mi][ni][reg];
      }
    }
}

// ---------- launcher ----------
extern "C" void kernel_launch(void* const* d_in, const int* in_sizes, int n_in,
                              void* d_out, int out_size, void* d_ws, size_t ws_size,
                              hipStream_t stream) {
  const float* x    = (const float*)d_in[0];
  const float* mask = (const float*)d_in[1];
  const float* ng   = (const float*)d_in[2];
  const float* nb   = (const float*)d_in[3];
  const float* Wl   = (const float*)d_in[4];
  const float* Wr   = (const float*)d_in[5];
  const float* Wlg  = (const float*)d_in[6];
  const float* Wrg  = (const float*)d_in[7];
  const float* Wog  = (const float*)d_in[8];
  const float* og   = (const float*)d_in[9];
  const float* ob   = (const float*)d_in[10];
  const float* Wout = (const float*)d_in[11];
  float* out = (float*)d_out;

  // workspace layout (bytes): xn/out_t share the first 64MB slab (xn dead after projections)
  const size_t SLAB = (size_t)NPOS_ * H_ * 2;  // 67,108,864
  char* ws = (char*)d_ws;
  u16* xn      = (u16*)(ws);
  u16* left_t  = (u16*)(ws + SLAB);
  u16* right_t = (u16*)(ws + 2 * SLAB);
  u16* gate_t  = (u16*)(ws + 3 * SLAB);
  u16* wb      = (u16*)(ws + 4 * SLAB);        // 6*128*128 bf16 = 196,608 B
  u16* out_t   = xn;                            // reuse slab 0 (after k_proj_* done)
  if (ws_size < 4 * SLAB + 6 * H_ * D_ * sizeof(u16)) return;

  k_prep<<<384, 256, 0, stream>>>(Wl, Wlg, Wr, Wrg, Wog, Wout, wb);
  k_ln<<<2048, 256, 0, stream>>>(x, ng, nb, (u32*)xn);
  k_proj_pair<<<dim3(2048, 2), 512, 0, stream>>>(xn, mask, wb, left_t, right_t);
  k_proj_gate<<<2048, 256, 0, stream>>>(xn, wb, gate_t);
  k_einsum<<<dim3(128, 16), 256, 0, stream>>>(left_t, right_t, out_t);
  k_final<<<2048, 256, 0, stream>>>(out_t, gate_t, og, ob, wb + 5 * H_ * D_, out);
}

// Round 3
// 591.802 us; speedup vs baseline: 1.0318x; 1.0318x over previous
//
#include <hip/hip_runtime.h>
#include <hip/hip_bf16.h>
#include <cstdint>

typedef unsigned short u16;
typedef unsigned int   u32;
typedef __bf16 bf16x8 __attribute__((ext_vector_type(8)));
typedef float  f32x4  __attribute__((ext_vector_type(4)));

#define S_    512
#define D_    128
#define H_    128
#define NPOS_ (S_ * S_)      // 262144 rows
#define LN_EPS 1e-5f

// ---------- small helpers ----------
__device__ __forceinline__ u16 f2bf(float f) {
  u32 u = __float_as_uint(f);
  u += 0x7fff + ((u >> 16) & 1);
  return (u16)(u >> 16);
}
__device__ __forceinline__ u32 f2bf2(float lo, float hi) {
  u32 a = __float_as_uint(lo); a += 0x7fff + ((a >> 16) & 1);
  u32 b = __float_as_uint(hi); b += 0x7fff + ((b >> 16) & 1);
  return (a >> 16) | (b & 0xffff0000u);
}
__device__ __forceinline__ float bflo(u32 p) { return __uint_as_float(p << 16); }
__device__ __forceinline__ float bfhi(u32 p) { return __uint_as_float(p & 0xffff0000u); }
__device__ __forceinline__ float sigmoidf_(float x) {
  return __builtin_amdgcn_rcpf(1.f + __expf(-x));
}

__device__ __forceinline__ void gld16(const void* g, void* l) {
  __builtin_amdgcn_global_load_lds(
      (const __attribute__((address_space(1))) void*)g,
      (__attribute__((address_space(3))) void*)l, 16, 0, 0);
}

// XOR-swizzled global->LDS stage (validated R2: kills 16-way conflicts, 0 on PMC)
template <int CPR, int TOTAL, int THREADS>
__device__ __forceinline__ void stage_sw(const char* gbase, int ld_bytes, char* lds, int tid) {
#pragma unroll
  for (int c = tid; c < TOTAL; c += THREADS) {
    int row  = c / CPR;
    int colL = c & (CPR - 1);
    int colG = colL ^ (row & (CPR - 1));
    gld16(gbase + (size_t)row * ld_bytes + (size_t)colG * 16, lds + (size_t)c * 16);
  }
}
__device__ __forceinline__ bf16x8 frag8(const u16* lds, int row, int ko) {   // 128B rows
  int chunk = (ko >> 3) ^ (row & 7);
  return *(const bf16x8*)&lds[row * 64 + (chunk << 3)];
}
__device__ __forceinline__ bf16x8 frag16(const u16* lds, int row, int ko) {  // 256B rows
  int chunk = (ko >> 3) ^ (row & 15);
  return *(const bf16x8*)&lds[row * 128 + (chunk << 3)];
}

// ---------- kernel 0: cast weights to bf16 ----------
// wb: [0]=Wl [1]=Wlg [2]=Wr [3]=Wrg [4]=Wog [5]=Wout, each 128x128 row-major
__global__ __launch_bounds__(256) void k_prep(
    const float* __restrict__ wl, const float* __restrict__ wlg,
    const float* __restrict__ wr, const float* __restrict__ wrg,
    const float* __restrict__ wog, const float* __restrict__ wout,
    u16* __restrict__ wb) {
  int i = blockIdx.x * 256 + threadIdx.x;
  int m = i >> 14, o = i & 16383;
  const float* src = (m == 0) ? wl : (m == 1) ? wlg : (m == 2) ? wr
                   : (m == 3) ? wrg : (m == 4) ? wog : wout;
  wb[i] = f2bf(src[o]);
}

// ---------- kernel 1: fused LN + 5 projections ----------
// Per block: 128 positions. x tile -> registers -> LN -> xn bf16 in LDS (resident),
// then 5 GEMMs vs W tiles streamed through a second LDS region.
// Outputs channel-major: left_t/right_t = value*mask*sigmoid(gateproj), gate_t = sigmoid(og proj).
__global__ __launch_bounds__(256, 2) void k_fused(
    const float* __restrict__ x, const float* __restrict__ mask,
    const float* __restrict__ ng, const float* __restrict__ nb,
    const u16* __restrict__ wb, u16* __restrict__ left_t,
    u16* __restrict__ right_t, u16* __restrict__ gate_t) {
  __shared__ u16 XN[128 * 128];   // 32 KB, frag16-swizzled, resident all 5 GEMMs
  __shared__ u16 WT[128 * 128];   // 32 KB, current weight tile
  const int tid = threadIdx.x, w = tid >> 6, l = tid & 63;
  const int r0 = blockIdx.x * 128;
  const int wr = w >> 1, wc = w & 1, quad = l >> 4, lc = l & 15;

  // --- LN phase: wave w owns local rows {w, w+4, ...} ---
  {
    const float2 gg = ((const float2*)ng)[l];
    const float2 bb = ((const float2*)nb)[l];
    for (int it = 0; it < 32; ++it) {
      int r = w + 4 * it;
      float2 v = ((const float2*)(x + (size_t)(r0 + r) * D_))[l];
      float s = v.x + v.y;
      float q = v.x * v.x + v.y * v.y;
#pragma unroll
      for (int off = 32; off >= 1; off >>= 1) {
        s += __shfl_xor(s, off);
        q += __shfl_xor(q, off);
      }
      float mu  = s * (1.f / 128.f);
      float var = q * (1.f / 128.f) - mu * mu;
      float rs  = rsqrtf(var + LN_EPS);
      u32 pk = f2bf2((v.x - mu) * rs * gg.x + bb.x, (v.y - mu) * rs * gg.y + bb.y);
      // d = 2l,2l+1 -> linear chunk l>>2, swizzle by row
      int chunk = (l >> 2) ^ (r & 15);
      *(u32*)((char*)XN + r * 256 + chunk * 16 + (l & 3) * 4) = pk;
    }
  }
  __syncthreads();

  float mk[4];
#pragma unroll
  for (int ni = 0; ni < 4; ++ni) mk[ni] = mask[r0 + wc * 64 + ni * 16 + lc];

  u32 sg_pk[4][4][2];              // packed sigmoid(gate-proj) stash
  const int widx[5] = {1, 0, 3, 2, 4};   // Wlg, Wl, Wrg, Wr, Wog

  for (int g = 0; g < 5; ++g) {
    stage_sw<16, 2048, 256>((const char*)(wb + (size_t)widx[g] * (H_ * D_)), 256, (char*)WT, tid);
    __syncthreads();
    const f32x4 vz = {0.f, 0.f, 0.f, 0.f};
    f32x4 acc[4][4];
#pragma unroll
    for (int i = 0; i < 4; ++i)
#pragma unroll
      for (int j = 0; j < 4; ++j) acc[i][j] = vz;
#pragma unroll
    for (int kk = 0; kk < 4; ++kk) {
      const int ko = kk * 32 + quad * 8;
      bf16x8 b[4];
#pragma unroll
      for (int ni = 0; ni < 4; ++ni)
        b[ni] = frag16(XN, wc * 64 + ni * 16 + lc, ko);
#pragma unroll
      for (int mi = 0; mi < 4; ++mi) {
        bf16x8 a = frag16(WT, wr * 64 + mi * 16 + lc, ko);
#pragma unroll
        for (int ni = 0; ni < 4; ++ni)
          acc[mi][ni] = __builtin_amdgcn_mfma_f32_16x16x32_bf16(a, b[ni], acc[mi][ni], 0, 0, 0);
      }
    }
    __syncthreads();   // WT dead -> next stage may overwrite

    if (g == 0 || g == 2) {        // gate projection: stash sigmoid
#pragma unroll
      for (int mi = 0; mi < 4; ++mi)
#pragma unroll
        for (int ni = 0; ni < 4; ++ni) {
          sg_pk[mi][ni][0] = f2bf2(sigmoidf_(acc[mi][ni][0]), sigmoidf_(acc[mi][ni][1]));
          sg_pk[mi][ni][1] = f2bf2(sigmoidf_(acc[mi][ni][2]), sigmoidf_(acc[mi][ni][3]));
        }
    } else if (g == 1 || g == 3) { // value projection: combine + store
      u16* dst = (g == 1) ? left_t : right_t;
#pragma unroll
      for (int mi = 0; mi < 4; ++mi)
#pragma unroll
        for (int ni = 0; ni < 4; ++ni) {
          float sg[4] = {bflo(sg_pk[mi][ni][0]), bfhi(sg_pk[mi][ni][0]),
                         bflo(sg_pk[mi][ni][1]), bfhi(sg_pk[mi][ni][1])};
          const int r = r0 + wc * 64 + ni * 16 + lc;
#pragma unroll
          for (int reg = 0; reg < 4; ++reg) {
            const int hrow = wr * 64 + mi * 16 + quad * 4 + reg;
            dst[(size_t)hrow * NPOS_ + r] = f2bf(acc[mi][ni][reg] * mk[ni] * sg[reg]);
          }
        }
    } else {                       // out-gate: sigmoid + store
#pragma unroll
      for (int mi = 0; mi < 4; ++mi)
#pragma unroll
        for (int ni = 0; ni < 4; ++ni) {
          const int r = r0 + wc * 64 + ni * 16 + lc;
#pragma unroll
          for (int reg = 0; reg < 4; ++reg) {
            const int hrow = wr * 64 + mi * 16 + quad * 4 + reg;
            gate_t[(size_t)hrow * NPOS_ + r] = f2bf(sigmoidf_(acc[mi][ni][reg]));
          }
        }
    }
  }
}

// ---------- kernel 2: per-channel einsum GEMM, 256x128 tiles ----------
// out_t[d][i*512+j] = sum_k left_t[d][i*512+k] * right_t[d][j*512+k]
__global__ __launch_bounds__(512, 4) void k_einsum(
    const u16* __restrict__ left_t, const u16* __restrict__ right_t,
    u16* __restrict__ out_t) {
  const int d = blockIdx.x;              // channel; XCD = d%8 (grid.x=128, 128%8==0)
  const int t = blockIdx.y;              // 0..7
  const int i0 = (t >> 2) * 256, j0 = (t & 3) * 128;
  __shared__ u16 As[256 * 64];           // 32 KB
  __shared__ u16 Bs[128 * 64];           // 16 KB
  const u16* L = left_t + (size_t)d * NPOS_;
  const u16* R = right_t + (size_t)d * NPOS_;
  const int tid = threadIdx.x;
  const int w = tid >> 6, l = tid & 63;
  const int wr = w >> 1, wc = w & 1;     // wave = 64x64 quadrant of 256x128

  const f32x4 vz = {0.f, 0.f, 0.f, 0.f};
  f32x4 acc[4][4];
#pragma unroll
  for (int i = 0; i < 4; ++i)
#pragma unroll
    for (int j = 0; j < 4; ++j) acc[i][j] = vz;

  for (int kt = 0; kt < 8; ++kt) {
    stage_sw<8, 2048, 512>((const char*)L + ((size_t)i0 * S_ + kt * 64) * 2, S_ * 2, (char*)As, tid);
    stage_sw<8, 1024, 512>((const char*)R + ((size_t)j0 * S_ + kt * 64) * 2, S_ * 2, (char*)Bs, tid);
    __syncthreads();
#pragma unroll
    for (int kk = 0; kk < 2; ++kk) {
      const int ko = kk * 32 + (l >> 4) * 8;
      bf16x8 a[4], b[4];
#pragma unroll
      for (int mi = 0; mi < 4; ++mi)
        a[mi] = frag8(As, wr * 64 + mi * 16 + (l & 15), ko);
#pragma unroll
      for (int ni = 0; ni < 4; ++ni)
        b[ni] = frag8(Bs, wc * 64 + ni * 16 + (l & 15), ko);
#pragma unroll
      for (int mi = 0; mi < 4; ++mi)
#pragma unroll
        for (int ni = 0; ni < 4; ++ni)
          acc[mi][ni] = __builtin_amdgcn_mfma_f32_16x16x32_bf16(a[mi], b[ni], acc[mi][ni], 0, 0, 0);
    }
    __syncthreads();
  }

  const int quad = l >> 4, lc = l & 15;
  u16* O = out_t + (size_t)d * NPOS_;
#pragma unroll
  for (int mi = 0; mi < 4; ++mi)
#pragma unroll
    for (int ni = 0; ni < 4; ++ni) {
      const int col = j0 + wc * 64 + ni * 16 + lc;
#pragma unroll
      for (int reg = 0; reg < 4; ++reg) {
        const int row = i0 + wr * 64 + mi * 16 + quad * 4 + reg;
        O[(size_t)row * S_ + col] = f2bf(acc[mi][ni][reg]);
      }
    }
}

// ---------- kernel 3: out-LN over H, gate, @Wout^T ----------
__global__ __launch_bounds__(256, 2) void k_final(
    const u16* __restrict__ out_t, const u16* __restrict__ gate_t,
    const float* __restrict__ og, const float* __restrict__ ob,
    const u16* __restrict__ wout_b, float* __restrict__ out) {
  __shared__ u16 A_lds[128 * 136];   // [position j][h], +8 padded rows
  __shared__ u16 Wlds[128 * 128];    // Wout [dout][h], swizzled
  __shared__ float psum[4][128], pq[4][128];
  __shared__ float mu_s[128], rs_s[128];
  const int tid = threadIdx.x, w = tid >> 6, l = tid & 63;
  const int r0 = blockIdx.x * 128;

  stage_sw<16, 2048, 256>((const char*)wout_b, 256, (char*)Wlds, tid);

  float s0 = 0.f, s1 = 0.f, q0 = 0.f, q1 = 0.f;
  for (int it = 0; it < 32; ++it) {
    int d = it * 4 + w;
    u32 p = *(const u32*)&out_t[(size_t)d * NPOS_ + r0 + 2 * l];
    float f0 = bflo(p), f1 = bfhi(p);
    s0 += f0; s1 += f1; q0 += f0 * f0; q1 += f1 * f1;
  }
  psum[w][2 * l] = s0; psum[w][2 * l + 1] = s1;
  pq[w][2 * l] = q0;   pq[w][2 * l + 1] = q1;
  __syncthreads();
  if (tid < 128) {
    float s = psum[0][tid] + psum[1][tid] + psum[2][tid] + psum[3][tid];
    float q = pq[0][tid] + pq[1][tid] + pq[2][tid] + pq[3][tid];
    float mu  = s * (1.f / 128.f);
    float var = q * (1.f / 128.f) - mu * mu;
    mu_s[tid] = mu;
    rs_s[tid] = rsqrtf(var + LN_EPS);
  }
  __syncthreads();

  for (int it = 0; it < 32; ++it) {
    int d = it * 4 + w;
    u32 p  = *(const u32*)&out_t[(size_t)d * NPOS_ + r0 + 2 * l];
    u32 gp = *(const u32*)&gate_t[(size_t)d * NPOS_ + r0 + 2 * l];
    float gd = og[d], bd = ob[d];
    float f0 = bflo(p), f1 = bfhi(p);
    float g0 = bflo(gp), g1 = bfhi(gp);
    int ja = 2 * l, jb = 2 * l + 1;
    A_lds[(size_t)ja * 136 + d] = f2bf(((f0 - mu_s[ja]) * rs_s[ja] * gd + bd) * g0);
    A_lds[(size_t)jb * 136 + d] = f2bf(((f1 - mu_s[jb]) * rs_s[jb] * gd + bd) * g1);
  }
  __syncthreads();

  const int wr = w >> 1, wc = w & 1;
  const f32x4 vz = {0.f, 0.f, 0.f, 0.f};
  f32x4 acc[4][4];
#pragma unroll
  for (int i = 0; i < 4; ++i)
#pragma unroll
    for (int j = 0; j < 4; ++j) acc[i][j] = vz;
#pragma unroll
  for (int kk = 0; kk < 4; ++kk) {
    const int ko = kk * 32 + (l >> 4) * 8;
    bf16x8 a[4], b[4];
#pragma unroll
    for (int mi = 0; mi < 4; ++mi)
      a[mi] = *(const bf16x8*)&A_lds[(wr * 64 + mi * 16 + (l & 15)) * 136 + ko];
#pragma unroll
    for (int ni = 0; ni < 4; ++ni)
      b[ni] = frag16(Wlds, wc * 64 + ni * 16 + (l & 15), ko);
#pragma unroll
    for (int mi = 0; mi < 4; ++mi)
#pragma unroll
      for (int ni = 0; ni < 4; ++ni)
        acc[mi][ni] = __builtin_amdgcn_mfma_f32_16x16x32_bf16(a[mi], b[ni], acc[mi][ni], 0, 0, 0);
  }
  const int quad = l >> 4, lc = l & 15;
#pragma unroll
  for (int mi = 0; mi < 4; ++mi)
#pragma unroll
    for (int ni = 0; ni < 4; ++ni) {
      const int dout = wc * 64 + ni * 16 + lc;
#pragma unroll
      for (int reg = 0; reg < 4; ++reg) {
        const int row = r0 + wr * 64 + mi * 16 + quad * 4 + reg;
        out[(size_t)row * D_ + dout] = acc[mi][ni][reg];
      }
    }
}

// ---------- launcher ----------
extern "C" void kernel_launch(void* const* d_in, const int* in_sizes, int n_in,
                              void* d_out, int out_size, void* d_ws, size_t ws_size,
                              hipStream_t stream) {
  const float* x    = (const float*)d_in[0];
  const float* mask = (const float*)d_in[1];
  const float* ng   = (const float*)d_in[2];
  const float* nb   = (const float*)d_in[3];
  const float* Wl   = (const float*)d_in[4];
  const float* Wr   = (const float*)d_in[5];
  const float* Wlg  = (const float*)d_in[6];
  const float* Wrg  = (const float*)d_in[7];
  const float* Wog  = (const float*)d_in[8];
  const float* og   = (const float*)d_in[9];
  const float* ob   = (const float*)d_in[10];
  const float* Wout = (const float*)d_in[11];
  float* out = (float*)d_out;

  const size_t SLAB = (size_t)NPOS_ * H_ * 2;  // 67,108,864
  char* ws = (char*)d_ws;
  u16* left_t  = (u16*)(ws);
  u16* right_t = (u16*)(ws + SLAB);
  u16* gate_t  = (u16*)(ws + 2 * SLAB);
  u16* out_t   = (u16*)(ws + 3 * SLAB);
  u16* wb      = (u16*)(ws + 4 * SLAB);        // 6*128*128 bf16
  if (ws_size < 4 * SLAB + 6 * H_ * D_ * sizeof(u16)) return;

  k_prep<<<384, 256, 0, stream>>>(Wl, Wlg, Wr, Wrg, Wog, Wout, wb);
  k_fused<<<2048, 256, 0, stream>>>(x, mask, ng, nb, wb, left_t, right_t, gate_t);
  k_einsum<<<dim3(128, 8), 512, 0, stream>>>(left_t, right_t, out_t);
  k_final<<<2048, 256, 0, stream>>>(out_t, gate_t, og, ob, wb + 5 * H_ * D_, out);
}